// Round 2
// baseline (1488.580 us; speedup 1.0000x reference)
//
#include <hip/hip_runtime.h>
#include <hip/hip_bf16.h>

#define B_ 4
#define S_ 4096
#define DM 512
#define DH 64

#define NEG_BIG (-3.0e38f)

// ---------------------------------------------------------------------------
// Dtype detector: scans first 2048 uint16 halves of q_in. bf16 N(0,1) data
// has exponent fields ~[96,134]; fp32 data reinterpreted as u16 has random
// exponent fields in ~42% of halves. flag=1 -> inputs are fp32.
// ---------------------------------------------------------------------------
__global__ void detect_kernel(const unsigned short* __restrict__ u,
                              int* __restrict__ flag) {
    __shared__ int cnt;
    if (threadIdx.x == 0) cnt = 0;
    __syncthreads();
    int w = 0;
    #pragma unroll
    for (int k = 0; k < 8; ++k) {
        unsigned short x = u[threadIdx.x * 8 + k];
        int e = (x >> 7) & 0xFF;
        if (e >= 135 || (e > 0 && e <= 95)) ++w;
    }
    atomicAdd(&cnt, w);
    __syncthreads();
    if (threadIdx.x == 0) *flag = (cnt > 64) ? 1 : 0;
}

// ---------------------------------------------------------------------------
// Projection: out[row,h] = sum_d x[row,d] * W[h,d] + b[h]   (torch Linear)
// grid.x = B*S rows, grid.y = 3 (q,k,v). block = 256.
// Each quad of threads computes one head h (4 x 128-dim partial dots).
// Input dtype chosen at runtime via *flag (0=bf16, 1=fp32).
// ---------------------------------------------------------------------------
__global__ __launch_bounds__(256) void proj_kernel(
    const void* __restrict__ xq, const void* __restrict__ xk,
    const void* __restrict__ xv,
    const void* __restrict__ Wq, const void* __restrict__ Wk,
    const void* __restrict__ Wv,
    const void* __restrict__ bq, const void* __restrict__ bk,
    const void* __restrict__ bv,
    float* __restrict__ Qo, float* __restrict__ Ko, float* __restrict__ Vo,
    const int* __restrict__ flag)
{
    const int which = blockIdx.y;
    const void* x    = (which == 0) ? xq : (which == 1) ? xk : xv;
    const void* W    = (which == 0) ? Wq : (which == 1) ? Wk : Wv;
    const void* bias = (which == 0) ? bq : (which == 1) ? bk : bv;
    float* out       = (which == 0) ? Qo : (which == 1) ? Ko : Vo;

    const bool f32 = (*flag != 0);
    const int row = blockIdx.x;
    const int tid = threadIdx.x;

    __shared__ float xsh[DM];
    if (f32) {
        const float2* xr =
            reinterpret_cast<const float2*>((const float*)x + (size_t)row * DM);
        float2 f = xr[tid];
        xsh[tid * 2]     = f.x;
        xsh[tid * 2 + 1] = f.y;
    } else {
        const __hip_bfloat162* xr = reinterpret_cast<const __hip_bfloat162*>(
            (const __hip_bfloat16*)x + (size_t)row * DM);
        float2 f = __bfloat1622float2(xr[tid]);
        xsh[tid * 2]     = f.x;
        xsh[tid * 2 + 1] = f.y;
    }
    __syncthreads();

    const int h     = tid >> 2;
    const int part  = tid & 3;
    const int dbase = part * 128;

    float sum = 0.f;
    if (f32) {
        const float4* wv4 = reinterpret_cast<const float4*>(
            (const float*)W + h * DM + dbase);
        #pragma unroll
        for (int c = 0; c < 32; ++c) {         // 32 x (4 f32) = 128 dims
            float4 w4 = wv4[c];
            sum = fmaf(xsh[dbase + c * 4 + 0], w4.x, sum);
            sum = fmaf(xsh[dbase + c * 4 + 1], w4.y, sum);
            sum = fmaf(xsh[dbase + c * 4 + 2], w4.z, sum);
            sum = fmaf(xsh[dbase + c * 4 + 3], w4.w, sum);
        }
    } else {
        const float4* wv4 = reinterpret_cast<const float4*>(
            (const __hip_bfloat16*)W + h * DM + dbase);
        #pragma unroll
        for (int c = 0; c < 16; ++c) {         // 16 x (8 bf16) = 128 dims
            float4 w4 = wv4[c];
            const __hip_bfloat162* wp = reinterpret_cast<const __hip_bfloat162*>(&w4);
            #pragma unroll
            for (int k2 = 0; k2 < 4; ++k2) {
                float2 wf = __bfloat1622float2(wp[k2]);
                sum = fmaf(xsh[dbase + c * 8 + k2 * 2],     wf.x, sum);
                sum = fmaf(xsh[dbase + c * 8 + k2 * 2 + 1], wf.y, sum);
            }
        }
    }
    // quad reduce (lanes of a quad are adjacent within a wave)
    sum += __shfl_xor(sum, 1);
    sum += __shfl_xor(sum, 2);
    if (part == 0) {
        float bv_ = f32 ? ((const float*)bias)[h]
                        : __bfloat162float(((const __hip_bfloat16*)bias)[h]);
        out[(size_t)row * DH + h] = sum + bv_;
    }
}

// ---------------------------------------------------------------------------
// Flash attention (causal). One block = 64 query rows of one batch.
// 256 threads: thread t -> query row i = t/4, col-group sub = t&3.
// Thread's 16 score cols are j = jj*4 + sub. Online softmax state (m,l)
// replicated across each quad via __shfl_xor. All math finite (no inf-inf).
// Output dtype chosen at runtime via *flag (0=bf16, 1=fp32).
// ---------------------------------------------------------------------------
#define LD 68   // LDS row stride in floats: 272 B, 16B-aligned, +4 banks/row

__global__ __launch_bounds__(256) void flash_kernel(
    const float* __restrict__ Q, const float* __restrict__ K,
    const float* __restrict__ V, void* __restrict__ out,
    const int* __restrict__ flag)
{
    const int qt   = blockIdx.x;       // 0..63
    const int b    = blockIdx.y;       // 0..3
    const int tid  = threadIdx.x;
    const int lane = tid & 63;
    const int i    = tid >> 2;         // query row in tile
    const int sub  = tid & 3;

    __shared__ float Qs[64][LD];
    __shared__ float Ks[64][LD];
    __shared__ float Vs[64][LD];

    const int    qbase     = qt * 64;
    const size_t batch_off = (size_t)b * S_ * DH;

    // load + scale Q tile: thread loads row tid/4, dims (tid&3)*16 .. +16
    {
        const int r  = tid >> 2;
        const int d0 = (tid & 3) * 16;
        const float4* src = reinterpret_cast<const float4*>(
            Q + batch_off + (size_t)(qbase + r) * DH + d0);
        #pragma unroll
        for (int c = 0; c < 4; ++c) {
            float4 f = src[c];
            Qs[r][d0 + c * 4 + 0] = f.x * 0.125f;   // 1/sqrt(64)
            Qs[r][d0 + c * 4 + 1] = f.y * 0.125f;
            Qs[r][d0 + c * 4 + 2] = f.z * 0.125f;
            Qs[r][d0 + c * 4 + 3] = f.w * 0.125f;
        }
    }

    float o[16];
    #pragma unroll
    for (int dd = 0; dd < 16; ++dd) o[dd] = 0.f;
    float m = NEG_BIG;
    float l = 0.f;

    for (int kt = 0; kt <= qt; ++kt) {
        __syncthreads();   // previous tile's reads done (also orders Q fill)
        {
            const int r  = tid >> 2;
            const int d0 = (tid & 3) * 16;
            const size_t goff = batch_off + (size_t)(kt * 64 + r) * DH + d0;
            const float4* ks = reinterpret_cast<const float4*>(K + goff);
            const float4* vs = reinterpret_cast<const float4*>(V + goff);
            #pragma unroll
            for (int c = 0; c < 4; ++c) {
                float4 f = ks[c];
                Ks[r][d0 + c * 4 + 0] = f.x;
                Ks[r][d0 + c * 4 + 1] = f.y;
                Ks[r][d0 + c * 4 + 2] = f.z;
                Ks[r][d0 + c * 4 + 3] = f.w;
                float4 g = vs[c];
                Vs[r][d0 + c * 4 + 0] = g.x;
                Vs[r][d0 + c * 4 + 1] = g.y;
                Vs[r][d0 + c * 4 + 2] = g.z;
                Vs[r][d0 + c * 4 + 3] = g.w;
            }
        }
        __syncthreads();

        // ---- scores: sc[jj] = q_i . k_{jj*4+sub} ----
        float sc[16];
        #pragma unroll
        for (int jj = 0; jj < 16; ++jj) sc[jj] = 0.f;
        for (int d0 = 0; d0 < 64; d0 += 4) {
            float4 q4 = *reinterpret_cast<const float4*>(&Qs[i][d0]);
            #pragma unroll
            for (int jj = 0; jj < 16; ++jj) {
                float4 k4 = *reinterpret_cast<const float4*>(&Ks[jj * 4 + sub][d0]);
                float s = sc[jj];
                s = fmaf(q4.x, k4.x, s);
                s = fmaf(q4.y, k4.y, s);
                s = fmaf(q4.z, k4.z, s);
                s = fmaf(q4.w, k4.w, s);
                sc[jj] = s;
            }
        }

        // causal mask: only the diagonal tile needs it (finite sentinel)
        if (kt == qt) {
            #pragma unroll
            for (int jj = 0; jj < 16; ++jj)
                if (jj * 4 + sub > i) sc[jj] = NEG_BIG;
        }

        // ---- online softmax (all finite) ----
        float mx = sc[0];
        #pragma unroll
        for (int jj = 1; jj < 16; ++jj) mx = fmaxf(mx, sc[jj]);
        mx = fmaxf(mx, __shfl_xor(mx, 1));
        mx = fmaxf(mx, __shfl_xor(mx, 2));
        const float m_new = fmaxf(m, mx);
        const float alpha = __expf(m - m_new);  // first tile: exp(-3e38)=0

        float p[16];
        float ps = 0.f;
        #pragma unroll
        for (int jj = 0; jj < 16; ++jj) {
            p[jj] = __expf(sc[jj] - m_new);     // masked -> underflow to 0
            ps += p[jj];
        }
        ps += __shfl_xor(ps, 1);
        ps += __shfl_xor(ps, 2);
        l = l * alpha + ps;
        m = m_new;
        #pragma unroll
        for (int dd = 0; dd < 16; ++dd) o[dd] *= alpha;

        // ---- PV: o[dd] += sum_j p_row[j] * V[j][sub*16+dd] ----
        const int qb = lane & ~3;
        #pragma unroll
        for (int j = 0; j < 64; ++j) {
            float pv = p[j >> 2];
            float pj = __shfl(pv, qb + (j & 3));
            const float4* v0 = reinterpret_cast<const float4*>(&Vs[j][sub * 16]);
            #pragma unroll
            for (int c = 0; c < 4; ++c) {
                float4 v4 = v0[c];
                o[c * 4 + 0] = fmaf(pj, v4.x, o[c * 4 + 0]);
                o[c * 4 + 1] = fmaf(pj, v4.y, o[c * 4 + 1]);
                o[c * 4 + 2] = fmaf(pj, v4.z, o[c * 4 + 2]);
                o[c * 4 + 3] = fmaf(pj, v4.w, o[c * 4 + 3]);
            }
        }
    }

    // epilogue: normalize, write in detected dtype
    const float inv = 1.0f / l;
    const size_t ooff = batch_off + (size_t)(qbase + i) * DH + sub * 16;
    if (*flag != 0) {
        float* op = (float*)out + ooff;
        #pragma unroll
        for (int dd = 0; dd < 16; ++dd) op[dd] = o[dd] * inv;
    } else {
        __hip_bfloat16* op = (__hip_bfloat16*)out + ooff;
        #pragma unroll
        for (int dd = 0; dd < 16; ++dd) op[dd] = __float2bfloat16(o[dd] * inv);
    }
}

extern "C" void kernel_launch(void* const* d_in, const int* in_sizes, int n_in,
                              void* d_out, int out_size, void* d_ws, size_t ws_size,
                              hipStream_t stream) {
    // workspace: Q,K,V projections in fp32 — 3 * 4*4096*64*4 B = 12 MB, + flag
    float* Qw = (float*)d_ws;
    float* Kw = Qw + (size_t)B_ * S_ * DH;
    float* Vw = Kw + (size_t)B_ * S_ * DH;
    int* flag = (int*)(Vw + (size_t)B_ * S_ * DH);

    detect_kernel<<<1, 256, 0, stream>>>((const unsigned short*)d_in[0], flag);

    proj_kernel<<<dim3(B_ * S_, 3), 256, 0, stream>>>(
        d_in[0], d_in[1], d_in[2],   // xq, xk, xv
        d_in[3], d_in[5], d_in[7],   // Wq, Wk, Wv
        d_in[4], d_in[6], d_in[8],   // bq, bk, bv
        Qw, Kw, Vw, flag);

    flash_kernel<<<dim3(S_ / 64, B_), 256, 0, stream>>>(
        Qw, Kw, Vw, d_out, flag);
}